// Round 17
// baseline (51.454 us; speedup 1.0000x reference)
//
#include <hip/hip_runtime.h>
#include <hip/hip_bf16.h>
#include <stdint.h>

using f32x4  = __attribute__((ext_vector_type(4))) float;
using bf16x8 = __attribute__((ext_vector_type(8))) __bf16;
using u16x4  = __attribute__((ext_vector_type(4))) unsigned short;
using u16x8  = __attribute__((ext_vector_type(8))) unsigned short;

#define DEVFN static __device__ __forceinline__

// ---------------- problem dims ----------------
constexpr int IND = 384, N1 = 512, N2R = 216, N2 = 256, NB = 10, NA = 2316;
constexpr int BATCH = 16384;
constexpr int RB  = 64;            // rows per block
constexpr int NC1 = 12;            // stage-1 K chunks (384/32)
constexpr int NC2 = 16;            // stage-2 K chunks (512/32)
constexpr int K3  = 224;           // stage-3 padded K

// ---------------- ws layout (u16 elements) ----------------
constexpr int WS_W1  = 0;                       // 12 chunks [512 col][32 k] swizzled
constexpr int WS_W2  = WS_W1 + NC1 * N1 * 32;   // 196608: 16 chunks [256 col][32 k]
constexpr int WS_W3  = WS_W2 + NC2 * N2 * 32;   // 327680: [16 col][224 k]
constexpr size_t WS_NEED = 708864;

// ---------------- LDS layout (byte offsets), phase-reused ----------------
constexpr int XT_OFF = 0;      constexpr int XT_ST = 784;   // [64][392] bf16 = 50176
constexpr int W1T    = 51200;                               // 3 x 32768 -> 149504
constexpr int H1_OFF = 0;      constexpr int H1_ST = 1040;  // [64][520] bf16 = 66560
constexpr int W2T    = 66560;                               // 3 x 16384 -> 115712 (aliases dead W1 bufs)
constexpr int H2_OFF = 0;      constexpr int H2_ST = 528;   // [64][264] bf16 = 33792
constexpr int W3_OFF = 115712;                              // 7168 -> 122880
constexpr int F_OFF  = 122880; constexpr int F_ST  = 48;    // [64][12] f32 -> 125952
constexpr int B1L    = 149504; // 512 f32
constexpr int B2L    = 151552; // 256 f32
constexpr int B3L    = 152576; // 16 f32
constexpr int LDS_E  = 152640;

DEVFN unsigned short bf16u(float f) {
    __hip_bfloat16 h = __float2bfloat16(f);
    unsigned short u; __builtin_memcpy(&u, &h, 2); return u;
}

DEVFN void mfma16(f32x4& d, bf16x8 a, bf16x8 b) {
    d = __builtin_amdgcn_mfma_f32_16x16x32_bf16(a, b, d, 0, 0, 0);
}

DEVFN void gll16(const void* g, void* lds) {
    __builtin_amdgcn_global_load_lds((const __attribute__((address_space(1))) void*)g,
                                     (__attribute__((address_space(3))) void*)lds, 16, 0, 0);
}

DEVFN void wait_vm4()   { asm volatile("s_waitcnt vmcnt(4)" ::: "memory"); }
DEVFN void wait_vm2()   { asm volatile("s_waitcnt vmcnt(2)" ::: "memory"); }
DEVFN void wait_vm0()   { asm volatile("s_waitcnt vmcnt(0)" ::: "memory"); }
DEVFN void wait_lgkm0() { asm volatile("s_waitcnt lgkmcnt(0)" ::: "memory"); }

// ============ pre-kernel v2: parallelized (113 blocks) fp32 -> bf16 swizzled image ============
__global__ __launch_bounds__(256)
void cvt_weights(const float* __restrict__ W1, const float* __restrict__ W2,
                 const float* __restrict__ W3,
                 unsigned short* __restrict__ ws)
{
    const int bid = blockIdx.x, tid = threadIdx.x;
    if (bid < 48) {
        const int c = bid >> 2, o = bid & 3;
        #pragma unroll
        for (int half = 0; half < 2; ++half) {
            const int col = half * 256 + tid;
            u16x8 v;
            #pragma unroll
            for (int s7 = 0; s7 < 8; ++s7)
                v[s7] = bf16u(W1[(size_t)(c * 32 + o * 8 + s7) * N1 + col]);
            *(u16x8*)(ws + WS_W1 + c * 16384 + col * 32 + ((o ^ (col & 3)) << 3)) = v;
        }
    } else if (bid < 112) {
        const int t = bid - 48;
        const int c = t >> 2, o = t & 3;
        const int col = tid;
        u16x8 v;
        #pragma unroll
        for (int s7 = 0; s7 < 8; ++s7) {
            int k = c * 32 + o * 8 + s7;
            v[s7] = (col < N2R) ? bf16u(W2[(size_t)k * N2R + col]) : (unsigned short)0;
        }
        *(u16x8*)(ws + WS_W2 + c * 8192 + col * 32 + ((o ^ (col & 3)) << 3)) = v;
    } else {
        for (int i = tid; i < 16 * K3; i += 256) {
            int col = i / K3, s = i - col * K3;
            int sb = s >> 5, r = s & 31;
            int k = sb * 32 + (((r >> 3) ^ (col & 3)) << 3) + (r & 7);
            float v = (col < NB && k < 216) ? W3[k * NB + col] : 0.f;
            ws[WS_W3 + i] = bf16u(v);
        }
    }
}

// ============ fused: stages 1-3 + head, one block = 64 rows end-to-end ============
__global__ __launch_bounds__(512)
void fused_mlp(const float* __restrict__ x,
               const float* __restrict__ b1g, const float* __restrict__ b2g,
               const float* __restrict__ b3g,
               const unsigned short* __restrict__ ws,
               const float* __restrict__ WhG, const float* __restrict__ bhg,
               float* __restrict__ out)
{
    __shared__ __attribute__((aligned(16))) unsigned char smem[LDS_E];
    const int tid  = threadIdx.x;
    const int wave = tid >> 6;
    const int lane = tid & 63;
    const int l16  = lane & 15;
    const int lk   = lane >> 4;
    const int wr   = wave >> 2;
    const int wc   = wave & 3;
    const int row0 = blockIdx.x * RB;

    const unsigned char* wsW1 = (const unsigned char*)(ws + WS_W1);
    const unsigned char* wsW2 = (const unsigned char*)(ws + WS_W2);

    // ---- W1 chunks 0,1 prefetch FIRST (latency overlaps x staging below) ----
    #pragma unroll
    for (int cc = 0; cc < 2; ++cc)
        #pragma unroll
        for (int o = 0; o < 4; ++o) {
            int wb = o * 8192 + wave * 1024;
            gll16(wsW1 + cc * 32768 + wb + lane * 16, smem + W1T + cc * 32768 + wb);
        }

    // ---- stage x tile [64][384] f32 -> bf16 LDS, + biases -> LDS ----
    {
        const float4* xg = (const float4*)(x + (size_t)row0 * IND);
        #pragma unroll
        for (int i = 0; i < 12; ++i) {
            int j = tid + i * 512;
            float4 v = xg[j];
            int el = j * 4, r = el / IND, c = el - r * IND;
            u16x4 h;
            h[0] = bf16u(v.x); h[1] = bf16u(v.y); h[2] = bf16u(v.z); h[3] = bf16u(v.w);
            *(u16x4*)(smem + XT_OFF + r * XT_ST + c * 2) = h;
        }
        *(float*)(smem + B1L + tid * 4) = b1g[tid];
        if (tid < 256) *(float*)(smem + B2L + tid * 4) = (tid < N2R) ? b2g[tid] : 0.f;
        if (tid < 16)  *(float*)(smem + B3L + tid * 4) = (tid < NB)  ? b3g[tid] : 0.f;
    }
    __syncthreads();   // full drain: vmcnt clean before counted pipeline

    // ================= Stage 1: h1 = relu(x @ W1 + b1), tribuf, 1 barrier/chunk =================
    // Wave-retile: each wave owns ALL 64 rows x 64 cols -> 4 A + 4 B ds_reads per chunk.
    // Iterations 10/11 prefetch W2 chunks 0/1 into W2T buf0/buf1 (aliases dead W1 bufs).
    f32x4 acc1[4][4] = {};

    for (int c = 0; c < NC1; ++c) {
        if (c + 1 < NC1) wait_vm4(); else wait_vm2();
        __builtin_amdgcn_s_barrier();      // buf[c%3] ready; readers of buf[(c+2)%3] done
        if (c + 2 < NC1) {
            const unsigned char* src = wsW1 + (size_t)(c + 2) * 32768;
            const int nxt = W1T + ((c + 2) % 3) * 32768;
            #pragma unroll
            for (int o = 0; o < 4; ++o) {
                int wb = o * 8192 + wave * 1024;
                gll16(src + wb + lane * 16, smem + nxt + wb);
            }
        } else {                            // c==10 -> W2 chunk0; c==11 -> W2 chunk1
            const int cc = c - 10;
            #pragma unroll
            for (int o = 0; o < 2; ++o) {
                int wb = o * 8192 + wave * 1024;
                gll16(wsW2 + cc * 16384 + wb + lane * 16, smem + W2T + cc * 16384 + wb);
            }
        }
        const int cur = W1T + (c % 3) * 32768;
        const int k0 = c * 32;
        bf16x8 a[4], b[4];
        #pragma unroll
        for (int m = 0; m < 4; ++m)
            a[m] = *(const bf16x8*)(smem + XT_OFF + (m * 16 + l16) * XT_ST + (k0 + lk * 8) * 2);
        #pragma unroll
        for (int n = 0; n < 4; ++n) {
            int col = wave * 64 + n * 16 + l16;
            b[n] = *(const bf16x8*)(smem + cur + col * 64 + ((lk ^ (col & 3)) << 4));
        }
        #pragma unroll
        for (int m = 0; m < 4; ++m)
            #pragma unroll
            for (int n = 0; n < 4; ++n)
                mfma16(acc1[m][n], a[m], b[n]);
    }
    __builtin_amdgcn_s_barrier();          // all waves done reading XT/bufs before H1 overwrite
    #pragma unroll
    for (int m = 0; m < 4; ++m)
        #pragma unroll
        for (int n = 0; n < 4; ++n) {
            int col = wave * 64 + n * 16 + l16;
            float bias = *(const float*)(smem + B1L + col * 4);
            #pragma unroll
            for (int e = 0; e < 4; ++e) {
                float v = fmaxf(acc1[m][n][e] + bias, 0.f);
                *(unsigned short*)(smem + H1_OFF + (m * 16 + lk * 4 + e) * H1_ST + col * 2) = bf16u(v);
            }
        }
    wait_lgkm0();
    __builtin_amdgcn_s_barrier();

    // ================= Stage 2: h2 = relu(h1 @ W2 + b2), tribuf (chunks 0,1 already in flight) =================
    f32x4 acc2[2][4] = {};

    for (int c = 0; c < NC2; ++c) {
        if (c + 1 < NC2) wait_vm2(); else wait_vm0();
        __builtin_amdgcn_s_barrier();
        if (c + 2 < NC2) {
            const unsigned char* src = wsW2 + (size_t)(c + 2) * 16384;
            const int nxt = W2T + ((c + 2) % 3) * 16384;
            #pragma unroll
            for (int o = 0; o < 2; ++o) {
                int wb = o * 8192 + wave * 1024;
                gll16(src + wb + lane * 16, smem + nxt + wb);
            }
        }
        const int cur = W2T + (c % 3) * 16384;
        const int k0 = c * 32;
        bf16x8 a0 = *(const bf16x8*)(smem + H1_OFF + (wr * 32 + l16)      * H1_ST + (k0 + lk * 8) * 2);
        bf16x8 a1 = *(const bf16x8*)(smem + H1_OFF + (wr * 32 + 16 + l16) * H1_ST + (k0 + lk * 8) * 2);
        #pragma unroll
        for (int n = 0; n < 4; ++n) {
            int col = wc * 64 + n * 16 + l16;
            bf16x8 b = *(const bf16x8*)(smem + cur + col * 64 + ((lk ^ (col & 3)) << 4));
            mfma16(acc2[0][n], a0, b);
            mfma16(acc2[1][n], a1, b);
        }
    }

    // ---- early Wh/bh register loads (main + TAIL): latency hides under stage-2
    //      epilogue + W3 stage + stage-3; the pre-stage-3 __syncthreads drains them.
    const int j0 = tid;                    // quads 0..511 (cols 0..2047)
    float w0[10][4];
    float4 bh0 = ((const float4*)bhg)[j0];
    #pragma unroll
    for (int k = 0; k < 10; ++k) {
        f32x4 q = *(const f32x4*)(WhG + (size_t)k * NA + j0 * 4);
        w0[k][0] = q[0]; w0[k][1] = q[1]; w0[k][2] = q[2]; w0[k][3] = q[3];
    }
    // tail items: idx = tid, tid+512 (and tid+1024 for tid<48, loaded inline later)
    const int qt0 = tid % 67,          rgt0 = tid / 67;
    const int qt1 = (tid + 512) % 67,  rgt1 = (tid + 512) / 67;
    float wt0[10][4], wt1[10][4];
    float4 bht0 = ((const float4*)bhg)[512 + qt0];
    float4 bht1 = ((const float4*)bhg)[512 + qt1];
    #pragma unroll
    for (int k = 0; k < 10; ++k) {
        f32x4 q = *(const f32x4*)(WhG + (size_t)k * NA + (512 + qt0) * 4);
        wt0[k][0] = q[0]; wt0[k][1] = q[1]; wt0[k][2] = q[2]; wt0[k][3] = q[3];
    }
    #pragma unroll
    for (int k = 0; k < 10; ++k) {
        f32x4 q = *(const f32x4*)(WhG + (size_t)k * NA + (512 + qt1) * 4);
        wt1[k][0] = q[0]; wt1[k][1] = q[1]; wt1[k][2] = q[2]; wt1[k][3] = q[3];
    }

    __builtin_amdgcn_s_barrier();          // all waves done reading H1 before H2 overwrite
    #pragma unroll
    for (int m = 0; m < 2; ++m)
        #pragma unroll
        for (int n = 0; n < 4; ++n) {
            int col = wc * 64 + n * 16 + l16;
            float bias = *(const float*)(smem + B2L + col * 4);
            #pragma unroll
            for (int e = 0; e < 4; ++e) {
                float v = fmaxf(acc2[m][n][e] + bias, 0.f);
                *(unsigned short*)(smem + H2_OFF + (wr * 32 + m * 16 + lk * 4 + e) * H2_ST + col * 2) = bf16u(v);
            }
        }
    if (wave < 7)
        gll16((const unsigned char*)(ws + WS_W3) + wave * 1024 + lane * 16, smem + W3_OFF + wave * 1024);
    __syncthreads();   // full drain (incl. W3 + Wh/tail loads)

    // ================= Stage 3: f = relu(h2 @ W3 + b3) (redundant across wc) =================
    f32x4 acc3[2] = {};
    #pragma unroll
    for (int c = 0; c < 7; ++c) {
        const int k0 = c * 32;
        bf16x8 a0 = *(const bf16x8*)(smem + H2_OFF + (wr * 32 + l16)      * H2_ST + (k0 + lk * 8) * 2);
        bf16x8 a1 = *(const bf16x8*)(smem + H2_OFF + (wr * 32 + 16 + l16) * H2_ST + (k0 + lk * 8) * 2);
        bf16x8 b  = *(const bf16x8*)(smem + W3_OFF + l16 * 448 + c * 64 + ((lk ^ (l16 & 3)) << 4));
        mfma16(acc3[0], a0, b);
        mfma16(acc3[1], a1, b);
    }
    if (wc == 0 && l16 < NB) {
        float bias = *(const float*)(smem + B3L + l16 * 4);
        #pragma unroll
        for (int m = 0; m < 2; ++m)
            #pragma unroll
            for (int e = 0; e < 4; ++e) {
                float v = fmaxf(acc3[m][e] + bias, 0.f);
                *(float*)(smem + F_OFF + (wr * 32 + m * 16 + lk * 4 + e) * F_ST + l16 * 4) = v;
            }
    }
    __syncthreads();   // f visible to all waves

    // ================= Head phase A: quads 0..511, wave-balanced =================
    #pragma unroll 1
    for (int rg = 0; rg < 16; ++rg) {
        float fv[4][10];
        #pragma unroll
        for (int rr = 0; rr < 4; ++rr) {
            const unsigned char* fb = smem + F_OFF + (rg * 4 + rr) * F_ST;
            f32x4 p0 = *(const f32x4*)(fb);
            f32x4 p1 = *(const f32x4*)(fb + 16);
            float2 p2 = *(const float2*)(fb + 32);
            fv[rr][0] = p0[0]; fv[rr][1] = p0[1]; fv[rr][2] = p0[2]; fv[rr][3] = p0[3];
            fv[rr][4] = p1[0]; fv[rr][5] = p1[1]; fv[rr][6] = p1[2]; fv[rr][7] = p1[3];
            fv[rr][8] = p2.x;  fv[rr][9] = p2.y;
        }
        float ac[4][4];
        #pragma unroll
        for (int rr = 0; rr < 4; ++rr) {
            ac[rr][0] = bh0.x; ac[rr][1] = bh0.y; ac[rr][2] = bh0.z; ac[rr][3] = bh0.w;
            #pragma unroll
            for (int k = 0; k < 10; ++k) {
                ac[rr][0] = fmaf(fv[rr][k], w0[k][0], ac[rr][0]);
                ac[rr][1] = fmaf(fv[rr][k], w0[k][1], ac[rr][1]);
                ac[rr][2] = fmaf(fv[rr][k], w0[k][2], ac[rr][2]);
                ac[rr][3] = fmaf(fv[rr][k], w0[k][3], ac[rr][3]);
            }
        }
        #pragma unroll
        for (int rr = 0; rr < 4; ++rr) {
            float4 o;
            o.x = ac[rr][0]; o.y = ac[rr][1]; o.z = ac[rr][2]; o.w = ac[rr][3];
            *(float4*)(out + (size_t)(row0 + rg * 4 + rr) * NA + j0 * 4) = o;
        }
    }

    // ================= Head phase B: tail quads 512..578, weights pre-hoisted =================
    {
        // item 0: idx = tid
        const int jq = 512 + qt0, rg = rgt0;
        #pragma unroll
        for (int rr = 0; rr < 4; ++rr) {
            const unsigned char* fb = smem + F_OFF + (rg * 4 + rr) * F_ST;
            f32x4 p0 = *(const f32x4*)(fb);
            f32x4 p1 = *(const f32x4*)(fb + 16);
            float2 p2 = *(const float2*)(fb + 32);
            float fr[10] = {p0[0],p0[1],p0[2],p0[3],p1[0],p1[1],p1[2],p1[3],p2.x,p2.y};
            float a0 = bht0.x, a1 = bht0.y, a2 = bht0.z, a3 = bht0.w;
            #pragma unroll
            for (int k = 0; k < 10; ++k) {
                a0 = fmaf(fr[k], wt0[k][0], a0);
                a1 = fmaf(fr[k], wt0[k][1], a1);
                a2 = fmaf(fr[k], wt0[k][2], a2);
                a3 = fmaf(fr[k], wt0[k][3], a3);
            }
            float4 o; o.x = a0; o.y = a1; o.z = a2; o.w = a3;
            *(float4*)(out + (size_t)(row0 + rg * 4 + rr) * NA + jq * 4) = o;
        }
    }
    {
        // item 1: idx = tid + 512
        const int jq = 512 + qt1, rg = rgt1;
        #pragma unroll
        for (int rr = 0; rr < 4; ++rr) {
            const unsigned char* fb = smem + F_OFF + (rg * 4 + rr) * F_ST;
            f32x4 p0 = *(const f32x4*)(fb);
            f32x4 p1 = *(const f32x4*)(fb + 16);
            float2 p2 = *(const float2*)(fb + 32);
            float fr[10] = {p0[0],p0[1],p0[2],p0[3],p1[0],p1[1],p1[2],p1[3],p2.x,p2.y};
            float a0 = bht1.x, a1 = bht1.y, a2 = bht1.z, a3 = bht1.w;
            #pragma unroll
            for (int k = 0; k < 10; ++k) {
                a0 = fmaf(fr[k], wt1[k][0], a0);
                a1 = fmaf(fr[k], wt1[k][1], a1);
                a2 = fmaf(fr[k], wt1[k][2], a2);
                a3 = fmaf(fr[k], wt1[k][3], a3);
            }
            float4 o; o.x = a0; o.y = a1; o.z = a2; o.w = a3;
            *(float4*)(out + (size_t)(row0 + rg * 4 + rr) * NA + jq * 4) = o;
        }
    }
    if (tid < 48) {
        // item 2: idx = tid + 1024 (only 48 threads; inline weight loads, L2-hot)
        const int idx = tid + 1024;
        const int q = idx % 67, rg = idx / 67;
        const int jq = 512 + q;
        float4 bhv = ((const float4*)bhg)[jq];
        float wt[10][4];
        #pragma unroll
        for (int k = 0; k < 10; ++k) {
            f32x4 qv = *(const f32x4*)(WhG + (size_t)k * NA + jq * 4);
            wt[k][0] = qv[0]; wt[k][1] = qv[1]; wt[k][2] = qv[2]; wt[k][3] = qv[3];
        }
        #pragma unroll
        for (int rr = 0; rr < 4; ++rr) {
            const unsigned char* fb = smem + F_OFF + (rg * 4 + rr) * F_ST;
            f32x4 p0 = *(const f32x4*)(fb);
            f32x4 p1 = *(const f32x4*)(fb + 16);
            float2 p2 = *(const float2*)(fb + 32);
            float fr[10] = {p0[0],p0[1],p0[2],p0[3],p1[0],p1[1],p1[2],p1[3],p2.x,p2.y};
            float a0 = bhv.x, a1 = bhv.y, a2 = bhv.z, a3 = bhv.w;
            #pragma unroll
            for (int k = 0; k < 10; ++k) {
                a0 = fmaf(fr[k], wt[k][0], a0);
                a1 = fmaf(fr[k], wt[k][1], a1);
                a2 = fmaf(fr[k], wt[k][2], a2);
                a3 = fmaf(fr[k], wt[k][3], a3);
            }
            float4 o; o.x = a0; o.y = a1; o.z = a2; o.w = a3;
            *(float4*)(out + (size_t)(row0 + rg * 4 + rr) * NA + jq * 4) = o;
        }
    }
}

extern "C" void kernel_launch(void* const* d_in, const int* in_sizes, int n_in,
                              void* d_out, int out_size, void* d_ws, size_t ws_size,
                              hipStream_t stream)
{
    const float* x  = (const float*)d_in[0];
    const float* W1 = (const float*)d_in[1];
    const float* b1 = (const float*)d_in[2];
    const float* W2 = (const float*)d_in[3];
    const float* b2 = (const float*)d_in[4];
    const float* W3 = (const float*)d_in[5];
    const float* b3 = (const float*)d_in[6];
    const float* Wh = (const float*)d_in[7];
    const float* bh = (const float*)d_in[8];
    unsigned short* ws = (unsigned short*)d_ws;
    float* out = (float*)d_out;

    if (ws_size < WS_NEED) return;

    cvt_weights<<<dim3(113), dim3(256), 0, stream>>>(W1, W2, W3, ws);
    fused_mlp<<<dim3(BATCH / RB), dim3(512), 0, stream>>>(x, b1, b2, b3, ws, Wh, bh, out);
}

// Round 18
// 50.138 us; speedup vs baseline: 1.0262x; 1.0262x over previous
//
#include <hip/hip_runtime.h>
#include <hip/hip_bf16.h>
#include <stdint.h>

using f32x4  = __attribute__((ext_vector_type(4))) float;
using bf16x8 = __attribute__((ext_vector_type(8))) __bf16;
using u16x4  = __attribute__((ext_vector_type(4))) unsigned short;
using u16x8  = __attribute__((ext_vector_type(8))) unsigned short;

#define DEVFN static __device__ __forceinline__

// ---------------- problem dims ----------------
constexpr int IND = 384, N1 = 512, N2R = 216, N2 = 256, NB = 10, NA = 2316;
constexpr int BATCH = 16384;
constexpr int RB  = 64;            // rows per block
constexpr int NC1 = 12;            // stage-1 K chunks (384/32)
constexpr int NC2 = 16;            // stage-2 K chunks (512/32)
constexpr int K3  = 224;           // stage-3 padded K

// ---------------- ws layout (u16 elements) ----------------
constexpr int WS_W1  = 0;                       // 12 chunks [512 col][32 k] swizzled
constexpr int WS_W2  = WS_W1 + NC1 * N1 * 32;   // 196608: 16 chunks [256 col][32 k]
constexpr int WS_W3  = WS_W2 + NC2 * N2 * 32;   // 327680: [16 col][224 k]
constexpr size_t WS_NEED = 708864;

// ---------------- LDS layout (byte offsets), phase-reused ----------------
constexpr int XT_OFF = 0;      constexpr int XT_ST = 784;   // [64][392] bf16 = 50176
constexpr int W1T    = 51200;                               // 3 x 32768 -> 149504
constexpr int H1_OFF = 0;      constexpr int H1_ST = 1040;  // [64][520] bf16 = 66560
constexpr int W2T    = 66560;                               // 3 x 16384 -> 115712 (aliases dead W1 bufs)
constexpr int H2_OFF = 0;      constexpr int H2_ST = 528;   // [64][264] bf16 = 33792
constexpr int W3_OFF = 115712;                              // 7168 -> 122880
constexpr int F_OFF  = 122880; constexpr int F_ST  = 48;    // [64][12] f32 -> 125952
constexpr int B1L    = 149504; // 512 f32
constexpr int B2L    = 151552; // 256 f32
constexpr int B3L    = 152576; // 16 f32
constexpr int LDS_E  = 152640;

DEVFN unsigned short bf16u(float f) {
    __hip_bfloat16 h = __float2bfloat16(f);
    unsigned short u; __builtin_memcpy(&u, &h, 2); return u;
}

DEVFN void mfma16(f32x4& d, bf16x8 a, bf16x8 b) {
    d = __builtin_amdgcn_mfma_f32_16x16x32_bf16(a, b, d, 0, 0, 0);
}

DEVFN void gll16(const void* g, void* lds) {
    __builtin_amdgcn_global_load_lds((const __attribute__((address_space(1))) void*)g,
                                     (__attribute__((address_space(3))) void*)lds, 16, 0, 0);
}

DEVFN void wait_vm4()   { asm volatile("s_waitcnt vmcnt(4)" ::: "memory"); }
DEVFN void wait_vm2()   { asm volatile("s_waitcnt vmcnt(2)" ::: "memory"); }
DEVFN void wait_vm0()   { asm volatile("s_waitcnt vmcnt(0)" ::: "memory"); }
DEVFN void wait_lgkm0() { asm volatile("s_waitcnt lgkmcnt(0)" ::: "memory"); }

// ============ pre-kernel v2: parallelized (113 blocks) fp32 -> bf16 swizzled image ============
__global__ __launch_bounds__(256)
void cvt_weights(const float* __restrict__ W1, const float* __restrict__ W2,
                 const float* __restrict__ W3,
                 unsigned short* __restrict__ ws)
{
    const int bid = blockIdx.x, tid = threadIdx.x;
    if (bid < 48) {
        const int c = bid >> 2, o = bid & 3;
        #pragma unroll
        for (int half = 0; half < 2; ++half) {
            const int col = half * 256 + tid;
            u16x8 v;
            #pragma unroll
            for (int s7 = 0; s7 < 8; ++s7)
                v[s7] = bf16u(W1[(size_t)(c * 32 + o * 8 + s7) * N1 + col]);
            *(u16x8*)(ws + WS_W1 + c * 16384 + col * 32 + ((o ^ (col & 3)) << 3)) = v;
        }
    } else if (bid < 112) {
        const int t = bid - 48;
        const int c = t >> 2, o = t & 3;
        const int col = tid;
        u16x8 v;
        #pragma unroll
        for (int s7 = 0; s7 < 8; ++s7) {
            int k = c * 32 + o * 8 + s7;
            v[s7] = (col < N2R) ? bf16u(W2[(size_t)k * N2R + col]) : (unsigned short)0;
        }
        *(u16x8*)(ws + WS_W2 + c * 8192 + col * 32 + ((o ^ (col & 3)) << 3)) = v;
    } else {
        for (int i = tid; i < 16 * K3; i += 256) {
            int col = i / K3, s = i - col * K3;
            int sb = s >> 5, r = s & 31;
            int k = sb * 32 + (((r >> 3) ^ (col & 3)) << 3) + (r & 7);
            float v = (col < NB && k < 216) ? W3[k * NB + col] : 0.f;
            ws[WS_W3 + i] = bf16u(v);
        }
    }
}

// ============ fused: stages 1-3 + head, one block = 64 rows end-to-end ============
__global__ __launch_bounds__(512)
void fused_mlp(const float* __restrict__ x,
               const float* __restrict__ b1g, const float* __restrict__ b2g,
               const float* __restrict__ b3g,
               const unsigned short* __restrict__ ws,
               const float* __restrict__ WhG, const float* __restrict__ bhg,
               float* __restrict__ out)
{
    __shared__ __attribute__((aligned(16))) unsigned char smem[LDS_E];
    const int tid  = threadIdx.x;
    const int wave = tid >> 6;
    const int lane = tid & 63;
    const int l16  = lane & 15;
    const int lk   = lane >> 4;
    const int wr   = wave >> 2;
    const int wc   = wave & 3;
    const int row0 = blockIdx.x * RB;

    const unsigned char* wsW1 = (const unsigned char*)(ws + WS_W1);
    const unsigned char* wsW2 = (const unsigned char*)(ws + WS_W2);

    // ---- W1 chunks 0,1 prefetch FIRST (latency overlaps x staging below) ----
    #pragma unroll
    for (int cc = 0; cc < 2; ++cc)
        #pragma unroll
        for (int o = 0; o < 4; ++o) {
            int wb = o * 8192 + wave * 1024;
            gll16(wsW1 + cc * 32768 + wb + lane * 16, smem + W1T + cc * 32768 + wb);
        }

    // ---- stage x tile [64][384] f32 -> bf16 LDS, + biases -> LDS ----
    {
        const float4* xg = (const float4*)(x + (size_t)row0 * IND);
        #pragma unroll
        for (int i = 0; i < 12; ++i) {
            int j = tid + i * 512;
            float4 v = xg[j];
            int el = j * 4, r = el / IND, c = el - r * IND;
            u16x4 h;
            h[0] = bf16u(v.x); h[1] = bf16u(v.y); h[2] = bf16u(v.z); h[3] = bf16u(v.w);
            *(u16x4*)(smem + XT_OFF + r * XT_ST + c * 2) = h;
        }
        *(float*)(smem + B1L + tid * 4) = b1g[tid];
        if (tid < 256) *(float*)(smem + B2L + tid * 4) = (tid < N2R) ? b2g[tid] : 0.f;
        if (tid < 16)  *(float*)(smem + B3L + tid * 4) = (tid < NB)  ? b3g[tid] : 0.f;
    }
    __syncthreads();   // full drain: vmcnt clean before counted pipeline

    // ================= Stage 1: h1 = relu(x @ W1 + b1), tribuf, 1 barrier/chunk =================
    // Wave-retile: each wave owns ALL 64 rows x 64 cols -> 4 A + 4 B ds_reads per chunk.
    // Iterations 10/11 prefetch W2 chunks 0/1 into W2T buf0/buf1 (aliases dead W1 bufs).
    f32x4 acc1[4][4] = {};

    for (int c = 0; c < NC1; ++c) {
        if (c + 1 < NC1) wait_vm4(); else wait_vm2();
        __builtin_amdgcn_s_barrier();      // buf[c%3] ready; readers of buf[(c+2)%3] done
        if (c + 2 < NC1) {
            const unsigned char* src = wsW1 + (size_t)(c + 2) * 32768;
            const int nxt = W1T + ((c + 2) % 3) * 32768;
            #pragma unroll
            for (int o = 0; o < 4; ++o) {
                int wb = o * 8192 + wave * 1024;
                gll16(src + wb + lane * 16, smem + nxt + wb);
            }
        } else {                            // c==10 -> W2 chunk0; c==11 -> W2 chunk1
            const int cc = c - 10;
            #pragma unroll
            for (int o = 0; o < 2; ++o) {
                int wb = o * 8192 + wave * 1024;
                gll16(wsW2 + cc * 16384 + wb + lane * 16, smem + W2T + cc * 16384 + wb);
            }
        }
        const int cur = W1T + (c % 3) * 32768;
        const int k0 = c * 32;
        bf16x8 a[4], b[4];
        #pragma unroll
        for (int m = 0; m < 4; ++m)
            a[m] = *(const bf16x8*)(smem + XT_OFF + (m * 16 + l16) * XT_ST + (k0 + lk * 8) * 2);
        #pragma unroll
        for (int n = 0; n < 4; ++n) {
            int col = wave * 64 + n * 16 + l16;
            b[n] = *(const bf16x8*)(smem + cur + col * 64 + ((lk ^ (col & 3)) << 4));
        }
        #pragma unroll
        for (int m = 0; m < 4; ++m)
            #pragma unroll
            for (int n = 0; n < 4; ++n)
                mfma16(acc1[m][n], a[m], b[n]);
    }
    __builtin_amdgcn_s_barrier();          // all waves done reading XT/bufs before H1 overwrite
    #pragma unroll
    for (int m = 0; m < 4; ++m)
        #pragma unroll
        for (int n = 0; n < 4; ++n) {
            int col = wave * 64 + n * 16 + l16;
            float bias = *(const float*)(smem + B1L + col * 4);
            #pragma unroll
            for (int e = 0; e < 4; ++e) {
                float v = fmaxf(acc1[m][n][e] + bias, 0.f);
                *(unsigned short*)(smem + H1_OFF + (m * 16 + lk * 4 + e) * H1_ST + col * 2) = bf16u(v);
            }
        }
    wait_lgkm0();
    __builtin_amdgcn_s_barrier();

    // ================= Stage 2: h2 = relu(h1 @ W2 + b2), tribuf (chunks 0,1 already in flight) =================
    f32x4 acc2[2][4] = {};

    for (int c = 0; c < NC2; ++c) {
        if (c + 1 < NC2) wait_vm2(); else wait_vm0();
        __builtin_amdgcn_s_barrier();
        if (c + 2 < NC2) {
            const unsigned char* src = wsW2 + (size_t)(c + 2) * 16384;
            const int nxt = W2T + ((c + 2) % 3) * 16384;
            #pragma unroll
            for (int o = 0; o < 2; ++o) {
                int wb = o * 8192 + wave * 1024;
                gll16(src + wb + lane * 16, smem + nxt + wb);
            }
        }
        const int cur = W2T + (c % 3) * 16384;
        const int k0 = c * 32;
        bf16x8 a0 = *(const bf16x8*)(smem + H1_OFF + (wr * 32 + l16)      * H1_ST + (k0 + lk * 8) * 2);
        bf16x8 a1 = *(const bf16x8*)(smem + H1_OFF + (wr * 32 + 16 + l16) * H1_ST + (k0 + lk * 8) * 2);
        #pragma unroll
        for (int n = 0; n < 4; ++n) {
            int col = wc * 64 + n * 16 + l16;
            bf16x8 b = *(const bf16x8*)(smem + cur + col * 64 + ((lk ^ (col & 3)) << 4));
            mfma16(acc2[0][n], a0, b);
            mfma16(acc2[1][n], a1, b);
        }
    }

    // ---- early Wh/bh register loads: latency hides under stage-2 epilogue + W3 stage + stage-3 ----
    const int j0 = tid;                    // quads 0..511 (cols 0..2047)
    float w0[10][4];
    float4 bh0 = ((const float4*)bhg)[j0];
    #pragma unroll
    for (int k = 0; k < 10; ++k) {
        f32x4 q = *(const f32x4*)(WhG + (size_t)k * NA + j0 * 4);
        w0[k][0] = q[0]; w0[k][1] = q[1]; w0[k][2] = q[2]; w0[k][3] = q[3];
    }

    __builtin_amdgcn_s_barrier();          // all waves done reading H1 before H2 overwrite
    #pragma unroll
    for (int m = 0; m < 2; ++m)
        #pragma unroll
        for (int n = 0; n < 4; ++n) {
            int col = wc * 64 + n * 16 + l16;
            float bias = *(const float*)(smem + B2L + col * 4);
            #pragma unroll
            for (int e = 0; e < 4; ++e) {
                float v = fmaxf(acc2[m][n][e] + bias, 0.f);
                *(unsigned short*)(smem + H2_OFF + (wr * 32 + m * 16 + lk * 4 + e) * H2_ST + col * 2) = bf16u(v);
            }
        }
    if (wave < 7)
        gll16((const unsigned char*)(ws + WS_W3) + wave * 1024 + lane * 16, smem + W3_OFF + wave * 1024);
    __syncthreads();   // full drain (incl. W3 + Wh loads)

    // ================= Stage 3: f = relu(h2 @ W3 + b3) (redundant across wc) =================
    f32x4 acc3[2] = {};
    #pragma unroll
    for (int c = 0; c < 7; ++c) {
        const int k0 = c * 32;
        bf16x8 a0 = *(const bf16x8*)(smem + H2_OFF + (wr * 32 + l16)      * H2_ST + (k0 + lk * 8) * 2);
        bf16x8 a1 = *(const bf16x8*)(smem + H2_OFF + (wr * 32 + 16 + l16) * H2_ST + (k0 + lk * 8) * 2);
        bf16x8 b  = *(const bf16x8*)(smem + W3_OFF + l16 * 448 + c * 64 + ((lk ^ (l16 & 3)) << 4));
        mfma16(acc3[0], a0, b);
        mfma16(acc3[1], a1, b);
    }
    if (wc == 0 && l16 < NB) {
        float bias = *(const float*)(smem + B3L + l16 * 4);
        #pragma unroll
        for (int m = 0; m < 2; ++m)
            #pragma unroll
            for (int e = 0; e < 4; ++e) {
                float v = fmaxf(acc3[m][e] + bias, 0.f);
                *(float*)(smem + F_OFF + (wr * 32 + m * 16 + lk * 4 + e) * F_ST + l16 * 4) = v;
            }
    }
    __syncthreads();   // f visible to all waves

    // ================= Head phase A: quads 0..511, wave-balanced (no has1 branch) =================
    #pragma unroll 1
    for (int rg = 0; rg < 16; ++rg) {
        float fv[4][10];
        #pragma unroll
        for (int rr = 0; rr < 4; ++rr) {
            const unsigned char* fb = smem + F_OFF + (rg * 4 + rr) * F_ST;
            f32x4 p0 = *(const f32x4*)(fb);
            f32x4 p1 = *(const f32x4*)(fb + 16);
            float2 p2 = *(const float2*)(fb + 32);
            fv[rr][0] = p0[0]; fv[rr][1] = p0[1]; fv[rr][2] = p0[2]; fv[rr][3] = p0[3];
            fv[rr][4] = p1[0]; fv[rr][5] = p1[1]; fv[rr][6] = p1[2]; fv[rr][7] = p1[3];
            fv[rr][8] = p2.x;  fv[rr][9] = p2.y;
        }
        float ac[4][4];
        #pragma unroll
        for (int rr = 0; rr < 4; ++rr) {
            ac[rr][0] = bh0.x; ac[rr][1] = bh0.y; ac[rr][2] = bh0.z; ac[rr][3] = bh0.w;
            #pragma unroll
            for (int k = 0; k < 10; ++k) {
                ac[rr][0] = fmaf(fv[rr][k], w0[k][0], ac[rr][0]);
                ac[rr][1] = fmaf(fv[rr][k], w0[k][1], ac[rr][1]);
                ac[rr][2] = fmaf(fv[rr][k], w0[k][2], ac[rr][2]);
                ac[rr][3] = fmaf(fv[rr][k], w0[k][3], ac[rr][3]);
            }
        }
        #pragma unroll
        for (int rr = 0; rr < 4; ++rr) {
            float4 o;
            o.x = ac[rr][0]; o.y = ac[rr][1]; o.z = ac[rr][2]; o.w = ac[rr][3];
            *(float4*)(out + (size_t)(row0 + rg * 4 + rr) * NA + j0 * 4) = o;
        }
    }

    // ================= Head phase B: tail quads 512..578 (67 x 16 items over all waves) =================
    #pragma unroll 1
    for (int idx = tid; idx < 67 * 16; idx += 512) {
        const int q  = idx % 67;
        const int rg = idx / 67;
        const int jq = 512 + q;
        float4 bhv = ((const float4*)bhg)[jq];
        float wt[10][4];
        #pragma unroll
        for (int k = 0; k < 10; ++k) {
            f32x4 qv = *(const f32x4*)(WhG + (size_t)k * NA + jq * 4);
            wt[k][0] = qv[0]; wt[k][1] = qv[1]; wt[k][2] = qv[2]; wt[k][3] = qv[3];
        }
        float fv[4][10];
        #pragma unroll
        for (int rr = 0; rr < 4; ++rr) {
            const unsigned char* fb = smem + F_OFF + (rg * 4 + rr) * F_ST;
            f32x4 p0 = *(const f32x4*)(fb);
            f32x4 p1 = *(const f32x4*)(fb + 16);
            float2 p2 = *(const float2*)(fb + 32);
            fv[rr][0] = p0[0]; fv[rr][1] = p0[1]; fv[rr][2] = p0[2]; fv[rr][3] = p0[3];
            fv[rr][4] = p1[0]; fv[rr][5] = p1[1]; fv[rr][6] = p1[2]; fv[rr][7] = p1[3];
            fv[rr][8] = p2.x;  fv[rr][9] = p2.y;
        }
        #pragma unroll
        for (int rr = 0; rr < 4; ++rr) {
            float a0 = bhv.x, a1 = bhv.y, a2 = bhv.z, a3 = bhv.w;
            #pragma unroll
            for (int k = 0; k < 10; ++k) {
                a0 = fmaf(fv[rr][k], wt[k][0], a0);
                a1 = fmaf(fv[rr][k], wt[k][1], a1);
                a2 = fmaf(fv[rr][k], wt[k][2], a2);
                a3 = fmaf(fv[rr][k], wt[k][3], a3);
            }
            float4 o; o.x = a0; o.y = a1; o.z = a2; o.w = a3;
            *(float4*)(out + (size_t)(row0 + rg * 4 + rr) * NA + jq * 4) = o;
        }
    }
}

extern "C" void kernel_launch(void* const* d_in, const int* in_sizes, int n_in,
                              void* d_out, int out_size, void* d_ws, size_t ws_size,
                              hipStream_t stream)
{
    const float* x  = (const float*)d_in[0];
    const float* W1 = (const float*)d_in[1];
    const float* b1 = (const float*)d_in[2];
    const float* W2 = (const float*)d_in[3];
    const float* b2 = (const float*)d_in[4];
    const float* W3 = (const float*)d_in[5];
    const float* b3 = (const float*)d_in[6];
    const float* Wh = (const float*)d_in[7];
    const float* bh = (const float*)d_in[8];
    unsigned short* ws = (unsigned short*)d_ws;
    float* out = (float*)d_out;

    if (ws_size < WS_NEED) return;

    cvt_weights<<<dim3(113), dim3(256), 0, stream>>>(W1, W2, W3, ws);
    fused_mlp<<<dim3(BATCH / RB), dim3(512), 0, stream>>>(x, b1, b2, b3, ws, Wh, bh, out);
}